// Round 2
// baseline (554.593 us; speedup 1.0000x reference)
//
#include <hip/hip_runtime.h>
#include <hip/hip_bf16.h>
#include <math.h>

// ============================================================================
// Generic fp32 GEMM: C[M,N] = A[M,K] @ W[K,N] + bias (+optional relu)
// Tile: 128(M) x 64(N), TK=16, 256 threads, 8x4 micro-tile per thread.
// ============================================================================
template<int RELU>
__global__ __launch_bounds__(256) void gemm_bias(
    const float* __restrict__ A, int lda,
    const float* __restrict__ W, int ldw,
    const float* __restrict__ bias,
    float* __restrict__ C, int ldc, int col_off,
    int M, int N, int K)
{
  __shared__ float As[16][132];
  __shared__ float Bs[16][68];
  const int tid = threadIdx.x;
  const int m0 = blockIdx.y * 128;
  const int n0 = blockIdx.x * 64;

  float acc[8][4];
#pragma unroll
  for (int i = 0; i < 8; i++)
#pragma unroll
    for (int j = 0; j < 4; j++) acc[i][j] = 0.f;

  const int a_k = tid & 15;
  const int a_m = tid >> 4;
  const int b_n = tid & 63;
  const int b_k = tid >> 6;
  const int rm = (tid >> 4) * 8;
  const int cn = (tid & 15) * 4;

  for (int k0 = 0; k0 < K; k0 += 16) {
#pragma unroll
    for (int i = 0; i < 8; i++)
      As[a_k][a_m + 16 * i] = A[(size_t)(m0 + a_m + 16 * i) * lda + (k0 + a_k)];
#pragma unroll
    for (int i = 0; i < 4; i++)
      Bs[b_k + 4 * i][b_n] = W[(size_t)(k0 + b_k + 4 * i) * ldw + (n0 + b_n)];
    __syncthreads();
#pragma unroll
    for (int k = 0; k < 16; k++) {
      float4 va0 = *(const float4*)&As[k][rm];
      float4 va1 = *(const float4*)&As[k][rm + 4];
      float4 vb  = *(const float4*)&Bs[k][cn];
      float av[8] = {va0.x, va0.y, va0.z, va0.w, va1.x, va1.y, va1.z, va1.w};
      float bv[4] = {vb.x, vb.y, vb.z, vb.w};
#pragma unroll
      for (int i = 0; i < 8; i++)
#pragma unroll
        for (int j = 0; j < 4; j++)
          acc[i][j] = fmaf(av[i], bv[j], acc[i][j]);
    }
    __syncthreads();
  }
#pragma unroll
  for (int i = 0; i < 8; i++) {
    const size_t m = (size_t)(m0 + rm + i);
#pragma unroll
    for (int j = 0; j < 4; j++) {
      const int n = n0 + cn + j;
      float v = acc[i][j] + bias[n];
      if (RELU) v = fmaxf(v, 0.f);
      C[m * ldc + col_off + n] = v;
    }
  }
}

// ============================================================================
// LayerNorm over last dim 256, in place. One wave per row (4 rows/block).
// ============================================================================
__global__ __launch_bounds__(256) void layernorm_kernel(
    float* __restrict__ a, const float* __restrict__ g, const float* __restrict__ b)
{
  const int row = blockIdx.x * 4 + (threadIdx.x >> 6);
  const int lane = threadIdx.x & 63;
  float4* p = (float4*)(a + (size_t)row * 256);
  float4 v = p[lane];
  float s = v.x + v.y + v.z + v.w;
#pragma unroll
  for (int off = 32; off > 0; off >>= 1) s += __shfl_down(s, off);
  const float mu = __shfl(s, 0) * (1.0f / 256.0f);
  const float dx = v.x - mu, dy = v.y - mu, dz = v.z - mu, dw = v.w - mu;
  float s2 = dx * dx + dy * dy + dz * dz + dw * dw;
#pragma unroll
  for (int off = 32; off > 0; off >>= 1) s2 += __shfl_down(s2, off);
  const float var = __shfl(s2, 0) * (1.0f / 256.0f);
  const float r = rsqrtf(var + 1e-5f);
  const float4 gg = ((const float4*)g)[lane];
  const float4 bb = ((const float4*)b)[lane];
  float4 o;
  o.x = dx * r * gg.x + bb.x;
  o.y = dy * r * gg.y + bb.y;
  o.z = dz * r * gg.z + bb.z;
  o.w = dw * r * gg.w + bb.w;
  p[lane] = o;
}

// ============================================================================
// Video: conv7x7(s2,p3) + spatial-mean folded into 49 tap-sums per (n,c).
// ============================================================================
__global__ __launch_bounds__(256) void video_reduce_kernel(
    const float* __restrict__ x, float* __restrict__ Sg)
{
  const int img = blockIdx.x;   // n*3 + c
  const float* p = x + (size_t)img * 12544;
  __shared__ float rowS[2][112];
  __shared__ float c0s[112], c1s[112], c109s[112], c110s[112], c111s[112];
  __shared__ float base[14];
  __shared__ float sE[7], sO[7];

  const int t = threadIdx.x;
  if (t < 224) {
    const int r = t >> 1;
    const int par = t & 1;
    const float* rp = p + r * 112 + par;
    float s = 0.f;
#pragma unroll
    for (int i = 0; i < 56; i++) s += rp[2 * i];
    rowS[par][r] = s;
    if (par == 0) {
      c0s[r] = rp[0];
      c110s[r] = rp[110];
    } else {
      c1s[r] = rp[0];
      c109s[r] = rp[108];
      c111s[r] = rp[110];
    }
  }
  __syncthreads();
  if (t < 14) {
    const int arr = t >> 1;
    const int rp = t & 1;
    const float* src = (arr == 0) ? rowS[0] : (arr == 1) ? rowS[1] :
                       (arr == 2) ? c0s : (arr == 3) ? c1s :
                       (arr == 4) ? c109s : (arr == 5) ? c110s : c111s;
    float s = 0.f;
    for (int r = rp; r < 112; r += 2) s += src[r];
    base[t] = s;
  }
  __syncthreads();
  if (t < 7) {
    float se, so;
    switch (t) {
      case 0: se = base[2] - base[8] - base[12]; so = base[3] - base[9] - base[13]; break;
      case 1: se = base[0] - base[10];           so = base[1] - base[11];           break;
      case 2: se = base[2] - base[12];           so = base[3] - base[13];           break;
      case 3: se = base[0];                      so = base[1];                      break;
      case 4: se = base[2];                      so = base[3];                      break;
      case 5: se = base[0] - base[4];            so = base[1] - base[5];            break;
      default: se = base[2] - base[6];           so = base[3] - base[7];            break;
    }
    sE[t] = se; sO[t] = so;
  }
  __syncthreads();
  if (t < 49) {
    const int kh = t / 7, kw = t % 7;
    auto ccol = [&](int r) -> float {
      switch (kw) {
        case 0: return rowS[1][r] - c109s[r] - c111s[r];
        case 1: return rowS[0][r] - c110s[r];
        case 2: return rowS[1][r] - c111s[r];
        case 3: return rowS[0][r];
        case 4: return rowS[1][r];
        case 5: return rowS[0][r] - c0s[r];
        default: return rowS[1][r] - c1s[r];
      }
    };
    float v;
    switch (kh) {
      case 0: v = sO[kw] - ccol(109) - ccol(111); break;
      case 1: v = sE[kw] - ccol(110);             break;
      case 2: v = sO[kw] - ccol(111);             break;
      case 3: v = sE[kw];                         break;
      case 4: v = sO[kw];                         break;
      case 5: v = sE[kw] - ccol(0);               break;
      default: v = sO[kw] - ccol(1);              break;
    }
    Sg[(size_t)img * 49 + t] = v;
  }
}

__global__ __launch_bounds__(64) void vpool_kernel(
    const float* __restrict__ Sg, const float* __restrict__ conv_w,
    const float* __restrict__ conv_b, float* __restrict__ vpool)
{
  __shared__ float s[147];
  const int n = blockIdx.x, o = threadIdx.x;
  for (int i = o; i < 147; i += 64) s[i] = Sg[(size_t)n * 147 + i];
  __syncthreads();
  float acc = 0.f;
#pragma unroll 7
  for (int k = 0; k < 147; k++) acc = fmaf(conv_w[o * 147 + k], s[k], acc);
  vpool[n * 64 + o] = conv_b[o] + acc / 3136.0f;
}

// ============================================================================
// Temporal interp TV=32 -> T=1024, writes into fbuf cols [256,512)
// ============================================================================
__global__ __launch_bounds__(256) void interp_video_kernel(
    const float* __restrict__ v256, float* __restrict__ fbuf)
{
  const int idx = blockIdx.x * 256 + threadIdx.x;
  const int c = idx & 255;
  const int t = (idx >> 8) & 1023;
  const int b = idx >> 18;
  float pos = ((float)t + 0.5f) * 0.03125f - 0.5f;
  pos = fminf(fmaxf(pos, 0.0f), 31.0f);
  const int lo = (int)floorf(pos);
  int hi = lo + 1; if (hi > 31) hi = 31;
  const float w = pos - (float)lo;
  const float vl = v256[(size_t)(b * 32 + lo) * 256 + c];
  const float vh = v256[(size_t)(b * 32 + hi) * 256 + c];
  fbuf[(size_t)(b * 1024 + t) * 512 + 256 + c] = vl * (1.0f - w) + vh * w;
}

// ============================================================================
// heads_w [4,256,80] -> Wp [256,320]; heads_b [4,80] -> bp [320]
// ============================================================================
__global__ __launch_bounds__(256) void repack_heads_kernel(
    const float* __restrict__ hw, const float* __restrict__ hb,
    float* __restrict__ Wp, float* __restrict__ bp)
{
  const int idx = blockIdx.x * 256 + threadIdx.x;
  const int col = idx % 320;
  const int d = idx / 320;
  const int s = col / 80, o = col % 80;
  Wp[idx] = hw[(size_t)(s * 256 + d) * 80 + o];
  if (idx < 320) bp[idx] = hb[(idx / 80) * 80 + (idx % 80)];
}

// ============================================================================
// specs_tmp [8192,320] -> d_out specs [B,S,T,80] + energy[b,s,t]=row sum
// ============================================================================
__global__ __launch_bounds__(256) void specs_energy_kernel(
    const float* __restrict__ stmp, float* __restrict__ out_specs,
    float* __restrict__ energy)
{
  const int idx = blockIdx.x * 256 + threadIdx.x;
  const int t = idx & 1023;
  const int s = (idx >> 10) & 3;
  const int b = idx >> 12;
  const float4* src = (const float4*)(stmp + (size_t)(b * 1024 + t) * 320 + s * 80);
  float4* dst = (float4*)(out_specs + (size_t)idx * 80);
  float sum = 0.f;
#pragma unroll
  for (int i = 0; i < 20; i++) {
    float4 v = src[i];
    dst[i] = v;
    sum += v.x + v.y + v.z + v.w;
  }
  energy[idx] = sum;
}

// ============================================================================
// Waveforms: JAX *partitionable* threefry2x32 (key=[0,1234]) + XLA erfinv.
// Per element n: counter64 = n -> (hi=0, lo=n); bits = x0 ^ x1 after 20 rounds.
// ============================================================================
__device__ __forceinline__ unsigned rotl32(unsigned x, int d) {
  return (x << d) | (x >> (32 - d));
}

__device__ __forceinline__ float erfinv_xla(float x) {
  float w = -log1pf(-x * x);
  float p;
  if (w < 5.0f) {
    w = w - 2.5f;
    p = 2.81022636e-08f;
    p = fmaf(p, w, 3.43273939e-07f);
    p = fmaf(p, w, -3.5233877e-06f);
    p = fmaf(p, w, -4.39150654e-06f);
    p = fmaf(p, w, 0.00021858087f);
    p = fmaf(p, w, -0.00125372503f);
    p = fmaf(p, w, -0.00417768164f);
    p = fmaf(p, w, 0.246640727f);
    p = fmaf(p, w, 1.50140941f);
  } else {
    w = sqrtf(w) - 3.0f;
    p = -0.000200214257f;
    p = fmaf(p, w, 0.000100950558f);
    p = fmaf(p, w, 0.00134934322f);
    p = fmaf(p, w, -0.00367342844f);
    p = fmaf(p, w, 0.00573950773f);
    p = fmaf(p, w, -0.0076224613f);
    p = fmaf(p, w, 0.00943887047f);
    p = fmaf(p, w, 1.00167406f);
    p = fmaf(p, w, 2.83297682f);
  }
  return p * x;
}

__global__ __launch_bounds__(256) void waveform_kernel(
    const float* __restrict__ energy, float* __restrict__ out)
{
  const unsigned n = blockIdx.x * 256 + threadIdx.x;   // [0, 5242880)
  const unsigned ks0 = 0u, ks1 = 1234u;
  const unsigned ks2 = 0x1BD11BDAu ^ ks0 ^ ks1;
  // partitionable path: x0 = counts_hi + ks0 = 0; x1 = counts_lo + ks1
  unsigned x0 = ks0;
  unsigned x1 = n + ks1;
#define TF_R4(a, b, c, d)                        \
  x0 += x1; x1 = rotl32(x1, a); x1 ^= x0;        \
  x0 += x1; x1 = rotl32(x1, b); x1 ^= x0;        \
  x0 += x1; x1 = rotl32(x1, c); x1 ^= x0;        \
  x0 += x1; x1 = rotl32(x1, d); x1 ^= x0;
  TF_R4(13, 15, 26, 6)  x0 += ks1; x1 += ks2 + 1u;
  TF_R4(17, 29, 16, 24) x0 += ks2; x1 += ks0 + 2u;
  TF_R4(13, 15, 26, 6)  x0 += ks0; x1 += ks1 + 3u;
  TF_R4(17, 29, 16, 24) x0 += ks1; x1 += ks2 + 4u;
  TF_R4(13, 15, 26, 6)  x0 += ks2; x1 += ks0 + 5u;
#undef TF_R4
  const unsigned bits = x0 ^ x1;

  // uniform in [nextafter(-1,0), 1)
  const float f = __uint_as_float((bits >> 9) | 0x3f800000u) - 1.0f;
  const float minv = -0.99999994f;
  const float u = fmaxf(minv, fmaf(f, 2.0f, minv));
  const float noise = 1.41421354f * erfinv_xla(u) * 0.1f;

  const unsigned i = n % 163840u;
  const unsigned bs = n / 163840u;
  float pos = ((float)i + 0.5f) * 0.00625f - 0.5f;
  pos = fminf(fmaxf(pos, 0.0f), 1023.0f);
  const int lo = (int)floorf(pos);
  int hi = lo + 1; if (hi > 1023) hi = 1023;
  const float w = pos - (float)lo;
  const float* e = energy + (size_t)bs * 1024;
  const float ev = e[lo] * (1.0f - w) + e[hi] * w;
  out[n] = noise * fmaf(ev, 0.5f, 0.5f);
}

// ============================================================================
// speaker_logits[b][s] = mean_t(f2[b,t,:]) @ w_spk + b_spk
// ============================================================================
__global__ __launch_bounds__(256) void speaker_kernel(
    const float* __restrict__ f2, const float* __restrict__ w_spk,
    const float* __restrict__ b_spk, float* __restrict__ out)
{
  const int b = blockIdx.x;
  const int c = threadIdx.x;
  float s = 0.f;
  for (int t = 0; t < 1024; t++) s += f2[((size_t)(b * 1024 + t)) * 256 + c];
  __shared__ float m[256];
  m[c] = s * (1.0f / 1024.0f);
  __syncthreads();
  if (c < 4) {
    float acc = 0.f;
    for (int d = 0; d < 256; d++) acc = fmaf(m[d], w_spk[d * 4 + c], acc);
    out[b * 4 + c] = acc + b_spk[c];
  }
}

// ============================================================================
extern "C" void kernel_launch(void* const* d_in, const int* in_sizes, int n_in,
                              void* d_out, int out_size, void* d_ws, size_t ws_size,
                              hipStream_t stream)
{
  (void)in_sizes; (void)n_in; (void)out_size; (void)ws_size;
  const float* audio   = (const float*)d_in[0];
  const float* video   = (const float*)d_in[1];
  const float* w_ae    = (const float*)d_in[2];
  const float* b_ae    = (const float*)d_in[3];
  const float* ln_g    = (const float*)d_in[4];
  const float* ln_b    = (const float*)d_in[5];
  const float* w_a1    = (const float*)d_in[6];
  const float* b_a1    = (const float*)d_in[7];
  const float* w_a2    = (const float*)d_in[8];
  const float* b_a2    = (const float*)d_in[9];
  const float* conv_w  = (const float*)d_in[10];
  const float* conv_b  = (const float*)d_in[11];
  const float* w_vfc   = (const float*)d_in[12];
  const float* b_vfc   = (const float*)d_in[13];
  const float* w_f1    = (const float*)d_in[14];
  const float* b_f1    = (const float*)d_in[15];
  const float* w_f2    = (const float*)d_in[16];
  const float* b_f2    = (const float*)d_in[17];
  const float* heads_w = (const float*)d_in[18];
  const float* heads_b = (const float*)d_in[19];
  const float* w_spk   = (const float*)d_in[20];
  const float* b_spk   = (const float*)d_in[21];

  float* ws = (float*)d_ws;
  float* a0     = ws;                 // 2,097,152  (a0/a_ln; later f2)
  float* h      = ws + 2097152;       // 4,194,304  (h1; later fmid)
  float* fbuf   = ws + 6291456;       // 4,194,304  (f concat; later specs_tmp)
  float* Sg     = ws + 10485760;      // 37,632
  float* vp     = ws + 10523392;      // 16,384
  float* v256   = ws + 10539776;      // 65,536
  float* Wp     = ws + 10605312;      // 81,920
  float* bp     = ws + 10687232;      // 320
  float* energy = ws + 10687552;      // 32,768

  float* out_wave   = (float*)d_out;           // 8*4*163840 = 5,242,880
  float* out_specs  = out_wave + 5242880;      // 8*4*1024*80 = 2,621,440
  float* out_logits = out_specs + 2621440;     // 32

  // ---- video branch ----
  video_reduce_kernel<<<768, 256, 0, stream>>>(video, Sg);
  vpool_kernel<<<256, 64, 0, stream>>>(Sg, conv_w, conv_b, vp);
  gemm_bias<0><<<dim3(4, 2), 256, 0, stream>>>(vp, 64, w_vfc, 256, b_vfc,
                                               v256, 256, 0, 256, 256, 64);

  // ---- audio branch ----
  gemm_bias<0><<<dim3(4, 64), 256, 0, stream>>>(audio, 80, w_ae, 256, b_ae,
                                                a0, 256, 0, 8192, 256, 80);
  layernorm_kernel<<<2048, 256, 0, stream>>>(a0, ln_g, ln_b);
  gemm_bias<1><<<dim3(8, 64), 256, 0, stream>>>(a0, 256, w_a1, 512, b_a1,
                                                h, 512, 0, 8192, 512, 256);
  gemm_bias<0><<<dim3(4, 64), 256, 0, stream>>>(h, 512, w_a2, 256, b_a2,
                                                fbuf, 512, 0, 8192, 256, 512);
  interp_video_kernel<<<8192, 256, 0, stream>>>(v256, fbuf);

  // ---- fusion ----
  gemm_bias<1><<<dim3(8, 64), 256, 0, stream>>>(fbuf, 512, w_f1, 512, b_f1,
                                                h, 512, 0, 8192, 512, 512);
  gemm_bias<0><<<dim3(4, 64), 256, 0, stream>>>(h, 512, w_f2, 256, b_f2,
                                                a0, 256, 0, 8192, 256, 512);

  // ---- heads -> specs + energy ----
  repack_heads_kernel<<<320, 256, 0, stream>>>(heads_w, heads_b, Wp, bp);
  gemm_bias<0><<<dim3(5, 64), 256, 0, stream>>>(a0, 256, Wp, 320, bp,
                                                fbuf, 320, 0, 8192, 320, 256);
  specs_energy_kernel<<<128, 256, 0, stream>>>(fbuf, out_specs, energy);

  // ---- waveforms (partitionable threefry noise * interpolated energy) ----
  waveform_kernel<<<20480, 256, 0, stream>>>(energy, out_wave);

  // ---- speaker logits ----
  speaker_kernel<<<8, 256, 0, stream>>>(a0, w_spk, b_spk, out_logits);
}

// Round 3
// 302.794 us; speedup vs baseline: 1.8316x; 1.8316x over previous
//
#include <hip/hip_runtime.h>
#include <hip/hip_bf16.h>
#include <math.h>

typedef _Float16 f16;
typedef f16 f16x8 __attribute__((ext_vector_type(8)));
typedef f16 f16x4 __attribute__((ext_vector_type(4)));
typedef float f32x4 __attribute__((ext_vector_type(4)));

#define GLOAD_LDS16(gp, lp) __builtin_amdgcn_global_load_lds(                 \
    (const __attribute__((address_space(1))) unsigned int*)(gp),              \
    (__attribute__((address_space(3))) unsigned int*)(lp), 16, 0, 0)

// ============================================================================
// fp16 MFMA GEMM: C[M,N] = A[M,K](f16) @ Wt[N,K]^T(f16) + bias(f32)
// Tile 128(M) x 64(N), BK=32, 256 threads = 4 waves (2x2), wave tile 64x32.
// MFMA 16x16x32_f16; A-frag A[m=lane&15][k=quad*8+j]; B-frag B[k][n=lane&15];
// D: col=lane&15 (n), row=quad*4+reg (m).   lda == K required (true here).
// ============================================================================
template<int RELU, int OUT16>
__global__ __launch_bounds__(256) void hgemm(
    const f16* __restrict__ A, const f16* __restrict__ Wt,
    const float* __restrict__ bias,
    void* __restrict__ Cout, int ldc, int col_off,
    int N, int K)
{
  __shared__ f16 As[128 * 32];   // [m][k] row-major, 64B rows
  __shared__ f16 Bs[64 * 32];    // [n][k] row-major
  const int tid = threadIdx.x;
  const int wave = tid >> 6, lane = tid & 63;
  const int wm = (wave >> 1) * 64;
  const int wn = (wave & 1) * 32;
  const int m0 = blockIdx.y * 128;
  const int n0 = blockIdx.x * 64;
  const int q = lane >> 4, r16 = lane & 15;

  f32x4 acc[4][2];
#pragma unroll
  for (int mi = 0; mi < 4; mi++)
#pragma unroll
    for (int ni = 0; ni < 2; ni++) acc[mi][ni] = (f32x4)0.f;

  for (int k0 = 0; k0 < K; k0 += 32) {
    // stage A tile 128x32 f16 (8KB): 2 x 16B per thread
#pragma unroll
    for (int i = 0; i < 2; i++) {
      const int o = (i * 256 + tid) * 16;       // byte offset in As
      const int row = o >> 6;                   // 64B per row
      const int col = (o & 63) >> 1;            // f16 col
      GLOAD_LDS16(A + (size_t)(m0 + row) * K + k0 + col, (char*)As + o);
    }
    { // stage B tile 64x32 f16 (4KB): 1 x 16B per thread
      const int o = tid * 16;
      const int row = o >> 6;
      const int col = (o & 63) >> 1;
      GLOAD_LDS16(Wt + (size_t)(n0 + row) * K + k0 + col, (char*)Bs + o);
    }
    __syncthreads();
    f16x8 af[4], bf[2];
#pragma unroll
    for (int mi = 0; mi < 4; mi++)
      af[mi] = *(const f16x8*)&As[(wm + mi * 16 + r16) * 32 + q * 8];
#pragma unroll
    for (int ni = 0; ni < 2; ni++)
      bf[ni] = *(const f16x8*)&Bs[(wn + ni * 16 + r16) * 32 + q * 8];
#pragma unroll
    for (int mi = 0; mi < 4; mi++)
#pragma unroll
      for (int ni = 0; ni < 2; ni++)
        acc[mi][ni] = __builtin_amdgcn_mfma_f32_16x16x32_f16(
            af[mi], bf[ni], acc[mi][ni], 0, 0, 0);
    __syncthreads();
  }

#pragma unroll
  for (int ni = 0; ni < 2; ni++) {
    const int n = n0 + wn + ni * 16 + r16;
    const float bv = bias[n];
#pragma unroll
    for (int mi = 0; mi < 4; mi++) {
#pragma unroll
      for (int rr = 0; rr < 4; rr++) {
        const int m = m0 + wm + mi * 16 + q * 4 + rr;
        float v = acc[mi][ni][rr] + bv;
        if (RELU) v = fmaxf(v, 0.f);
        if (OUT16) ((f16*)Cout)[(size_t)m * ldc + col_off + n] = (f16)v;
        else       ((float*)Cout)[(size_t)m * ldc + col_off + n] = v;
      }
    }
  }
}

// ============================================================================
// fp32 GEMM kept for the tiny video FC (M=256,K=64)
// ============================================================================
template<int RELU>
__global__ __launch_bounds__(256) void gemm_bias(
    const float* __restrict__ A, int lda,
    const float* __restrict__ W, int ldw,
    const float* __restrict__ bias,
    float* __restrict__ C, int ldc, int col_off,
    int M, int N, int K)
{
  __shared__ float As[16][132];
  __shared__ float Bs[16][68];
  const int tid = threadIdx.x;
  const int m0 = blockIdx.y * 128;
  const int n0 = blockIdx.x * 64;
  float acc[8][4];
#pragma unroll
  for (int i = 0; i < 8; i++)
#pragma unroll
    for (int j = 0; j < 4; j++) acc[i][j] = 0.f;
  const int a_k = tid & 15;
  const int a_m = tid >> 4;
  const int b_n = tid & 63;
  const int b_k = tid >> 6;
  const int rm = (tid >> 4) * 8;
  const int cn = (tid & 15) * 4;
  for (int k0 = 0; k0 < K; k0 += 16) {
#pragma unroll
    for (int i = 0; i < 8; i++)
      As[a_k][a_m + 16 * i] = A[(size_t)(m0 + a_m + 16 * i) * lda + (k0 + a_k)];
#pragma unroll
    for (int i = 0; i < 4; i++)
      Bs[b_k + 4 * i][b_n] = W[(size_t)(k0 + b_k + 4 * i) * ldw + (n0 + b_n)];
    __syncthreads();
#pragma unroll
    for (int k = 0; k < 16; k++) {
      float4 va0 = *(const float4*)&As[k][rm];
      float4 va1 = *(const float4*)&As[k][rm + 4];
      float4 vb  = *(const float4*)&Bs[k][cn];
      float av[8] = {va0.x, va0.y, va0.z, va0.w, va1.x, va1.y, va1.z, va1.w};
      float bv[4] = {vb.x, vb.y, vb.z, vb.w};
#pragma unroll
      for (int i = 0; i < 8; i++)
#pragma unroll
        for (int j = 0; j < 4; j++)
          acc[i][j] = fmaf(av[i], bv[j], acc[i][j]);
    }
    __syncthreads();
  }
#pragma unroll
  for (int i = 0; i < 8; i++) {
    const size_t m = (size_t)(m0 + rm + i);
#pragma unroll
    for (int j = 0; j < 4; j++) {
      const int n = n0 + cn + j;
      float v = acc[i][j] + bias[n];
      if (RELU) v = fmaxf(v, 0.f);
      C[m * ldc + col_off + n] = v;
    }
  }
}

// ============================================================================
// Weight convert + transpose to [N][K] f16 (+ heads repack, bp copy)
// ============================================================================
__global__ __launch_bounds__(256) void convert_weights(
    const float* __restrict__ w_ae, const float* __restrict__ w_a1,
    const float* __restrict__ w_a2, const float* __restrict__ w_f1,
    const float* __restrict__ w_f2, const float* __restrict__ heads_w,
    const float* __restrict__ heads_b,
    f16* __restrict__ wae_t, f16* __restrict__ wa1_t, f16* __restrict__ wa2_t,
    f16* __restrict__ wf1_t, f16* __restrict__ wf2_t, f16* __restrict__ wh_t,
    float* __restrict__ bp)
{
  int idx = blockIdx.x * 256 + threadIdx.x;
  if (idx < 24576) {  // wae_t [256][96], pad k>=80 with 0
    int n = idx / 96, k = idx % 96;
    wae_t[idx] = (f16)(k < 80 ? w_ae[k * 256 + n] : 0.f);
    return;
  }
  idx -= 24576;
  if (idx < 131072) { int n = idx >> 8, k = idx & 255; wa1_t[idx] = (f16)w_a1[k * 512 + n]; return; }
  idx -= 131072;
  if (idx < 131072) { int n = idx >> 9, k = idx & 511; wa2_t[idx] = (f16)w_a2[k * 256 + n]; return; }
  idx -= 131072;
  if (idx < 262144) { int n = idx >> 9, k = idx & 511; wf1_t[idx] = (f16)w_f1[k * 512 + n]; return; }
  idx -= 262144;
  if (idx < 131072) { int n = idx >> 9, k = idx & 511; wf2_t[idx] = (f16)w_f2[k * 256 + n]; return; }
  idx -= 131072;
  if (idx < 81920) {  // wh_t [320][256]: n=s*80+o, k=d
    int n = idx >> 8, d = idx & 255;
    int s = n / 80, o = n % 80;
    wh_t[idx] = (f16)heads_w[(size_t)(s * 256 + d) * 80 + o];
    return;
  }
  idx -= 81920;
  if (idx < 320) bp[idx] = heads_b[idx];
}

__global__ __launch_bounds__(256) void convert_audio(
    const float* __restrict__ audio, f16* __restrict__ a_h)
{
  const int idx = blockIdx.x * 256 + threadIdx.x;   // 786432
  const int row = idx / 96, col = idx % 96;
  a_h[idx] = (f16)(col < 80 ? audio[(size_t)row * 80 + col] : 0.f);
}

// ============================================================================
// LayerNorm(256) reading fp32, writing fp16. One wave per row.
// ============================================================================
__global__ __launch_bounds__(256) void layernorm_f16(
    const float* __restrict__ a, const float* __restrict__ g,
    const float* __restrict__ b, f16* __restrict__ out)
{
  const int row = blockIdx.x * 4 + (threadIdx.x >> 6);
  const int lane = threadIdx.x & 63;
  const float4 v = ((const float4*)(a + (size_t)row * 256))[lane];
  float s = v.x + v.y + v.z + v.w;
#pragma unroll
  for (int off = 32; off > 0; off >>= 1) s += __shfl_down(s, off);
  const float mu = __shfl(s, 0) * (1.0f / 256.0f);
  const float dx = v.x - mu, dy = v.y - mu, dz = v.z - mu, dw = v.w - mu;
  float s2 = dx * dx + dy * dy + dz * dz + dw * dw;
#pragma unroll
  for (int off = 32; off > 0; off >>= 1) s2 += __shfl_down(s2, off);
  const float var = __shfl(s2, 0) * (1.0f / 256.0f);
  const float r = rsqrtf(var + 1e-5f);
  const float4 gg = ((const float4*)g)[lane];
  const float4 bb = ((const float4*)b)[lane];
  f16x4 o;
  o[0] = (f16)(dx * r * gg.x + bb.x);
  o[1] = (f16)(dy * r * gg.y + bb.y);
  o[2] = (f16)(dz * r * gg.z + bb.z);
  o[3] = (f16)(dw * r * gg.w + bb.w);
  ((f16x4*)(out + (size_t)row * 256))[lane] = o;
}

// ============================================================================
// Video: conv7x7(s2,p3)+spatial-mean folded into 49 tap-sums per (n,c).
// ============================================================================
__global__ __launch_bounds__(256) void video_reduce_kernel(
    const float* __restrict__ x, float* __restrict__ Sg)
{
  const int img = blockIdx.x;
  const float* p = x + (size_t)img * 12544;
  __shared__ float rowS[2][112];
  __shared__ float c0s[112], c1s[112], c109s[112], c110s[112], c111s[112];
  __shared__ float base[14];
  __shared__ float sE[7], sO[7];
  const int t = threadIdx.x;
  if (t < 224) {
    const int r = t >> 1;
    const int par = t & 1;
    const float* rp = p + r * 112 + par;
    float s = 0.f;
#pragma unroll
    for (int i = 0; i < 56; i++) s += rp[2 * i];
    rowS[par][r] = s;
    if (par == 0) { c0s[r] = rp[0]; c110s[r] = rp[110]; }
    else { c1s[r] = rp[0]; c109s[r] = rp[108]; c111s[r] = rp[110]; }
  }
  __syncthreads();
  if (t < 14) {
    const int arr = t >> 1;
    const int rp = t & 1;
    const float* src = (arr == 0) ? rowS[0] : (arr == 1) ? rowS[1] :
                       (arr == 2) ? c0s : (arr == 3) ? c1s :
                       (arr == 4) ? c109s : (arr == 5) ? c110s : c111s;
    float s = 0.f;
    for (int r = rp; r < 112; r += 2) s += src[r];
    base[t] = s;
  }
  __syncthreads();
  if (t < 7) {
    float se, so;
    switch (t) {
      case 0: se = base[2] - base[8] - base[12]; so = base[3] - base[9] - base[13]; break;
      case 1: se = base[0] - base[10];           so = base[1] - base[11];           break;
      case 2: se = base[2] - base[12];           so = base[3] - base[13];           break;
      case 3: se = base[0];                      so = base[1];                      break;
      case 4: se = base[2];                      so = base[3];                      break;
      case 5: se = base[0] - base[4];            so = base[1] - base[5];            break;
      default: se = base[2] - base[6];           so = base[3] - base[7];            break;
    }
    sE[t] = se; sO[t] = so;
  }
  __syncthreads();
  if (t < 49) {
    const int kh = t / 7, kw = t % 7;
    auto ccol = [&](int r) -> float {
      switch (kw) {
        case 0: return rowS[1][r] - c109s[r] - c111s[r];
        case 1: return rowS[0][r] - c110s[r];
        case 2: return rowS[1][r] - c111s[r];
        case 3: return rowS[0][r];
        case 4: return rowS[1][r];
        case 5: return rowS[0][r] - c0s[r];
        default: return rowS[1][r] - c1s[r];
      }
    };
    float v;
    switch (kh) {
      case 0: v = sO[kw] - ccol(109) - ccol(111); break;
      case 1: v = sE[kw] - ccol(110);             break;
      case 2: v = sO[kw] - ccol(111);             break;
      case 3: v = sE[kw];                         break;
      case 4: v = sO[kw];                         break;
      case 5: v = sE[kw] - ccol(0);               break;
      default: v = sO[kw] - ccol(1);              break;
    }
    Sg[(size_t)img * 49 + t] = v;
  }
}

__global__ __launch_bounds__(64) void vpool_kernel(
    const float* __restrict__ Sg, const float* __restrict__ conv_w,
    const float* __restrict__ conv_b, float* __restrict__ vpool)
{
  __shared__ float s[147];
  const int n = blockIdx.x, o = threadIdx.x;
  for (int i = o; i < 147; i += 64) s[i] = Sg[(size_t)n * 147 + i];
  __syncthreads();
  float acc = 0.f;
#pragma unroll 7
  for (int k = 0; k < 147; k++) acc = fmaf(conv_w[o * 147 + k], s[k], acc);
  vpool[n * 64 + o] = conv_b[o] + acc / 3136.0f;
}

// Temporal interp TV=32 -> T=1024, writes f16 into fbuf16 cols [256,512)
__global__ __launch_bounds__(256) void interp_video_f16(
    const float* __restrict__ v256, f16* __restrict__ fbuf)
{
  const int idx = blockIdx.x * 256 + threadIdx.x;
  const int c = idx & 255;
  const int t = (idx >> 8) & 1023;
  const int b = idx >> 18;
  float pos = ((float)t + 0.5f) * 0.03125f - 0.5f;
  pos = fminf(fmaxf(pos, 0.0f), 31.0f);
  const int lo = (int)floorf(pos);
  int hi = lo + 1; if (hi > 31) hi = 31;
  const float w = pos - (float)lo;
  const float vl = v256[(size_t)(b * 32 + lo) * 256 + c];
  const float vh = v256[(size_t)(b * 32 + hi) * 256 + c];
  fbuf[(size_t)(b * 1024 + t) * 512 + 256 + c] = (f16)(vl * (1.0f - w) + vh * w);
}

// specs_tmp [8192,320] f32 -> out specs [B,S,T,80] + energy row sums
__global__ __launch_bounds__(256) void specs_energy_kernel(
    const float* __restrict__ stmp, float* __restrict__ out_specs,
    float* __restrict__ energy)
{
  const int idx = blockIdx.x * 256 + threadIdx.x;   // 32768 = B*S*T
  const int t = idx & 1023;
  const int s = (idx >> 10) & 3;
  const int b = idx >> 12;
  const float4* src = (const float4*)(stmp + (size_t)(b * 1024 + t) * 320 + s * 80);
  float4* dst = (float4*)(out_specs + (size_t)idx * 80);
  float sum = 0.f;
#pragma unroll
  for (int i = 0; i < 20; i++) {
    float4 v = src[i];
    dst[i] = v;
    sum += v.x + v.y + v.z + v.w;
  }
  energy[idx] = sum;
}

// ============================================================================
// Waveforms: JAX partitionable threefry2x32 (key=[0,1234]) + XLA erfinv
// ============================================================================
__device__ __forceinline__ unsigned rotl32(unsigned x, int d) {
  return (x << d) | (x >> (32 - d));
}

__device__ __forceinline__ float erfinv_xla(float x) {
  float w = -log1pf(-x * x);
  float p;
  if (w < 5.0f) {
    w = w - 2.5f;
    p = 2.81022636e-08f;
    p = fmaf(p, w, 3.43273939e-07f);
    p = fmaf(p, w, -3.5233877e-06f);
    p = fmaf(p, w, -4.39150654e-06f);
    p = fmaf(p, w, 0.00021858087f);
    p = fmaf(p, w, -0.00125372503f);
    p = fmaf(p, w, -0.00417768164f);
    p = fmaf(p, w, 0.246640727f);
    p = fmaf(p, w, 1.50140941f);
  } else {
    w = sqrtf(w) - 3.0f;
    p = -0.000200214257f;
    p = fmaf(p, w, 0.000100950558f);
    p = fmaf(p, w, 0.00134934322f);
    p = fmaf(p, w, -0.00367342844f);
    p = fmaf(p, w, 0.00573950773f);
    p = fmaf(p, w, -0.0076224613f);
    p = fmaf(p, w, 0.00943887047f);
    p = fmaf(p, w, 1.00167406f);
    p = fmaf(p, w, 2.83297682f);
  }
  return p * x;
}

__global__ __launch_bounds__(256) void waveform_kernel(
    const float* __restrict__ energy, float* __restrict__ out)
{
  const unsigned n = blockIdx.x * 256 + threadIdx.x;   // [0, 5242880)
  const unsigned ks0 = 0u, ks1 = 1234u;
  const unsigned ks2 = 0x1BD11BDAu ^ ks0 ^ ks1;
  unsigned x0 = ks0;
  unsigned x1 = n + ks1;
#define TF_R4(a, b, c, d)                        \
  x0 += x1; x1 = rotl32(x1, a); x1 ^= x0;        \
  x0 += x1; x1 = rotl32(x1, b); x1 ^= x0;        \
  x0 += x1; x1 = rotl32(x1, c); x1 ^= x0;        \
  x0 += x1; x1 = rotl32(x1, d); x1 ^= x0;
  TF_R4(13, 15, 26, 6)  x0 += ks1; x1 += ks2 + 1u;
  TF_R4(17, 29, 16, 24) x0 += ks2; x1 += ks0 + 2u;
  TF_R4(13, 15, 26, 6)  x0 += ks0; x1 += ks1 + 3u;
  TF_R4(17, 29, 16, 24) x0 += ks1; x1 += ks2 + 4u;
  TF_R4(13, 15, 26, 6)  x0 += ks2; x1 += ks0 + 5u;
#undef TF_R4
  const unsigned bits = x0 ^ x1;
  const float f = __uint_as_float((bits >> 9) | 0x3f800000u) - 1.0f;
  const float minv = -0.99999994f;
  const float u = fmaxf(minv, fmaf(f, 2.0f, minv));
  const float noise = 1.41421354f * erfinv_xla(u) * 0.1f;
  const unsigned i = n % 163840u;
  const unsigned bs = n / 163840u;
  float pos = ((float)i + 0.5f) * 0.00625f - 0.5f;
  pos = fminf(fmaxf(pos, 0.0f), 1023.0f);
  const int lo = (int)floorf(pos);
  int hi = lo + 1; if (hi > 1023) hi = 1023;
  const float w = pos - (float)lo;
  const float* e = energy + (size_t)bs * 1024;
  const float ev = e[lo] * (1.0f - w) + e[hi] * w;
  out[n] = noise * fmaf(ev, 0.5f, 0.5f);
}

// speaker_logits[b][s] = mean_t(f2[b,t,:]) @ w_spk + b_spk  (f2 in f16)
__global__ __launch_bounds__(256) void speaker_kernel(
    const f16* __restrict__ f2, const float* __restrict__ w_spk,
    const float* __restrict__ b_spk, float* __restrict__ out)
{
  const int b = blockIdx.x;
  const int c = threadIdx.x;
  float s = 0.f;
  for (int t = 0; t < 1024; t++) s += (float)f2[((size_t)(b * 1024 + t)) * 256 + c];
  __shared__ float m[256];
  m[c] = s * (1.0f / 1024.0f);
  __syncthreads();
  if (c < 4) {
    float acc = 0.f;
    for (int d = 0; d < 256; d++) acc = fmaf(m[d], w_spk[d * 4 + c], acc);
    out[b * 4 + c] = acc + b_spk[c];
  }
}

// ============================================================================
extern "C" void kernel_launch(void* const* d_in, const int* in_sizes, int n_in,
                              void* d_out, int out_size, void* d_ws, size_t ws_size,
                              hipStream_t stream)
{
  (void)in_sizes; (void)n_in; (void)out_size; (void)ws_size;
  const float* audio   = (const float*)d_in[0];
  const float* video   = (const float*)d_in[1];
  const float* w_ae    = (const float*)d_in[2];
  const float* b_ae    = (const float*)d_in[3];
  const float* ln_g    = (const float*)d_in[4];
  const float* ln_b    = (const float*)d_in[5];
  const float* w_a1    = (const float*)d_in[6];
  const float* b_a1    = (const float*)d_in[7];
  const float* w_a2    = (const float*)d_in[8];
  const float* b_a2    = (const float*)d_in[9];
  const float* conv_w  = (const float*)d_in[10];
  const float* conv_b  = (const float*)d_in[11];
  const float* w_vfc   = (const float*)d_in[12];
  const float* b_vfc   = (const float*)d_in[13];
  const float* w_f1    = (const float*)d_in[14];
  const float* b_f1    = (const float*)d_in[15];
  const float* w_f2    = (const float*)d_in[16];
  const float* b_f2    = (const float*)d_in[17];
  const float* heads_w = (const float*)d_in[18];
  const float* heads_b = (const float*)d_in[19];
  const float* w_spk   = (const float*)d_in[20];
  const float* b_spk   = (const float*)d_in[21];

  float* ws = (float*)d_ws;
  float* a0   = ws;               // 2,097,152 f32
  float* stmp = ws + 2097152;     // 2,621,440 f32
  f16* h16base = (f16*)(ws + 4718592);
  f16* a1     = h16base;                  // 2,097,152 f16 (also f2_16)
  f16* h16    = a1 + 2097152;             // 4,194,304 f16 (also layer4 out)
  f16* fbuf16 = h16 + 4194304;            // 4,194,304 f16
  f16* a_h    = fbuf16 + 4194304;         //   786,432 f16
  f16* wae_t  = a_h + 786432;             //    24,576
  f16* wa1_t  = wae_t + 24576;            //   131,072
  f16* wa2_t  = wa1_t + 131072;           //   131,072
  f16* wf1_t  = wa2_t + 131072;           //   262,144
  f16* wf2_t  = wf1_t + 262144;           //   131,072
  f16* wh_t   = wf2_t + 131072;           //    81,920
  float* tail = (float*)(wh_t + 81920);
  // align tail to 16B
  tail = (float*)(((uintptr_t)tail + 15) & ~(uintptr_t)15);
  float* Sg     = tail;             // 37,632
  float* vp     = Sg + 37632;       // 16,384
  float* v256   = vp + 16384;       // 65,536
  float* bp     = v256 + 65536;     // 320
  float* energy = bp + 320;         // 32,768

  float* out_wave   = (float*)d_out;           // 5,242,880
  float* out_specs  = out_wave + 5242880;      // 2,621,440
  float* out_logits = out_specs + 2621440;     // 32

  // ---- conversions ----
  convert_weights<<<2978, 256, 0, stream>>>(w_ae, w_a1, w_a2, w_f1, w_f2,
                                            heads_w, heads_b,
                                            wae_t, wa1_t, wa2_t, wf1_t, wf2_t,
                                            wh_t, bp);
  convert_audio<<<3072, 256, 0, stream>>>(audio, a_h);

  // ---- video branch ----
  video_reduce_kernel<<<768, 256, 0, stream>>>(video, Sg);
  vpool_kernel<<<256, 64, 0, stream>>>(Sg, conv_w, conv_b, vp);
  gemm_bias<0><<<dim3(4, 2), 256, 0, stream>>>(vp, 64, w_vfc, 256, b_vfc,
                                               v256, 256, 0, 256, 256, 64);

  // ---- audio branch (fp16 MFMA) ----
  hgemm<0, 0><<<dim3(4, 64), 256, 0, stream>>>(a_h, wae_t, b_ae, a0, 256, 0, 256, 96);
  layernorm_f16<<<2048, 256, 0, stream>>>(a0, ln_g, ln_b, a1);
  hgemm<1, 1><<<dim3(8, 64), 256, 0, stream>>>(a1, wa1_t, b_a1, h16, 512, 0, 512, 256);
  hgemm<0, 1><<<dim3(4, 64), 256, 0, stream>>>(h16, wa2_t, b_a2, fbuf16, 512, 0, 256, 512);
  interp_video_f16<<<8192, 256, 0, stream>>>(v256, fbuf16);

  // ---- fusion (fp16 MFMA) ----
  hgemm<1, 1><<<dim3(8, 64), 256, 0, stream>>>(fbuf16, wf1_t, b_f1, h16, 512, 0, 512, 512);
  hgemm<0, 1><<<dim3(4, 64), 256, 0, stream>>>(h16, wf2_t, b_f2, a1, 256, 0, 256, 512);

  // ---- heads -> specs + energy ----
  hgemm<0, 0><<<dim3(5, 64), 256, 0, stream>>>(a1, wh_t, bp, stmp, 320, 0, 320, 256);
  specs_energy_kernel<<<128, 256, 0, stream>>>(stmp, out_specs, energy);

  // ---- waveforms ----
  waveform_kernel<<<20480, 256, 0, stream>>>(energy, out_wave);

  // ---- speaker logits ----
  speaker_kernel<<<8, 256, 0, stream>>>(a1, w_spk, b_spk, out_logits);
}

// Round 4
// 263.755 us; speedup vs baseline: 2.1027x; 1.1480x over previous
//
#include <hip/hip_runtime.h>
#include <hip/hip_bf16.h>
#include <math.h>

typedef _Float16 f16;
typedef f16 f16x8 __attribute__((ext_vector_type(8)));
typedef f16 f16x4 __attribute__((ext_vector_type(4)));
typedef float f32x4 __attribute__((ext_vector_type(4)));

// ============================================================================
// fp16 MFMA GEMM: C[M,N] = A[M,K](f16) @ Wt[N,K]^T(f16) + bias(f32)
// Tile 128(M) x 64(N), BK=64, 256 threads = 4 waves (2x2), wave tile 64x32.
// LDS tiles are [row][64 k] with XOR-swizzled 16B granules:
//   phys_granule = (k>>3) ^ (row & 7)   -> conflict-free b128 reads/writes.
// OUT: 0 = f32 store; 1 = f16 store; 2 = f16 store + colsum atomics (speaker);
//      3 = f32 store remapped to specs [B,S,T,80] layout.
// ============================================================================
template<int RELU, int OUT>
__global__ __launch_bounds__(256) void hgemm(
    const f16* __restrict__ A, const f16* __restrict__ Wt,
    const float* __restrict__ bias,
    void* __restrict__ Cout, int ldc, int col_off,
    int N, int K, float* __restrict__ colsum)
{
  __shared__ f16 As[128 * 64];   // 16 KB, 128B rows
  __shared__ f16 Bs[64 * 64];    // 8 KB
  const int tid = threadIdx.x;
  const int wave = tid >> 6, lane = tid & 63;
  const int wm = (wave >> 1) * 64;
  const int wn = (wave & 1) * 32;
  const int m0 = blockIdx.y * 128;
  const int n0 = blockIdx.x * 64;
  const int q = lane >> 4, r16 = lane & 15;

  f32x4 acc[4][2];
#pragma unroll
  for (int mi = 0; mi < 4; mi++)
#pragma unroll
    for (int ni = 0; ni < 2; ni++) acc[mi][ni] = (f32x4)0.f;

  for (int k0 = 0; k0 < K; k0 += 64) {
    // ---- global -> registers (coalesced 16B/lane) ----
    f16x8 areg[4], breg[2];
#pragma unroll
    for (int i = 0; i < 4; i++) {
      const int G = i * 256 + tid, row = G >> 3, g = G & 7;
      areg[i] = *(const f16x8*)(A + (size_t)(m0 + row) * K + k0 + g * 8);
    }
#pragma unroll
    for (int i = 0; i < 2; i++) {
      const int G = i * 256 + tid, row = G >> 3, g = G & 7;
      breg[i] = *(const f16x8*)(Wt + (size_t)(n0 + row) * K + k0 + g * 8);
    }
    // ---- registers -> LDS (swizzled) ----
#pragma unroll
    for (int i = 0; i < 4; i++) {
      const int G = i * 256 + tid, row = G >> 3, g = G & 7;
      *(f16x8*)((char*)As + row * 128 + ((g ^ (row & 7)) * 16)) = areg[i];
    }
#pragma unroll
    for (int i = 0; i < 2; i++) {
      const int G = i * 256 + tid, row = G >> 3, g = G & 7;
      *(f16x8*)((char*)Bs + row * 128 + ((g ^ (row & 7)) * 16)) = breg[i];
    }
    __syncthreads();
    // ---- LDS -> fragments -> MFMA (two 32-wide k halves) ----
#pragma unroll
    for (int h = 0; h < 2; h++) {
      const int kg = h * 4 + q;   // 16B granule within the 64-col row
      f16x8 af[4], bf[2];
#pragma unroll
      for (int mi = 0; mi < 4; mi++) {
        const int row = wm + mi * 16 + r16;
        af[mi] = *(const f16x8*)((char*)As + row * 128 + ((kg ^ (row & 7)) * 16));
      }
#pragma unroll
      for (int ni = 0; ni < 2; ni++) {
        const int row = wn + ni * 16 + r16;
        bf[ni] = *(const f16x8*)((char*)Bs + row * 128 + ((kg ^ (row & 7)) * 16));
      }
#pragma unroll
      for (int mi = 0; mi < 4; mi++)
#pragma unroll
        for (int ni = 0; ni < 2; ni++)
          acc[mi][ni] = __builtin_amdgcn_mfma_f32_16x16x32_f16(
              af[mi], bf[ni], acc[mi][ni], 0, 0, 0);
    }
    __syncthreads();
  }

#pragma unroll
  for (int ni = 0; ni < 2; ni++) {
    const int n = n0 + wn + ni * 16 + r16;
    const float bv = bias[n];
    const int s_ = n / 80, o_ = n - s_ * 80;   // OUT==3 only
    float csum = 0.f;
#pragma unroll
    for (int mi = 0; mi < 4; mi++) {
#pragma unroll
      for (int rr = 0; rr < 4; rr++) {
        const int m = m0 + wm + mi * 16 + q * 4 + rr;
        float v = acc[mi][ni][rr] + bv;
        if (RELU) v = fmaxf(v, 0.f);
        if (OUT == 2) csum += v;
        if (OUT == 0)
          ((float*)Cout)[(size_t)m * ldc + col_off + n] = v;
        else if (OUT == 3) {
          const int b_ = m >> 10, t_ = m & 1023;
          ((float*)Cout)[((size_t)((b_ * 4 + s_) * 1024 + t_)) * 80 + o_] = v;
        } else
          ((f16*)Cout)[(size_t)m * ldc + col_off + n] = (f16)v;
      }
    }
    if (OUT == 2) {
      csum += __shfl_xor(csum, 16);
      csum += __shfl_xor(csum, 32);
      if (q == 0) atomicAdd(&colsum[(m0 >> 10) * 256 + n], csum);
    }
  }
}

// ============================================================================
// Prep: all weight transposes to [N][K] f16, audio pad->f16, bias copy,
// colsum zero. One dispatch.
// ============================================================================
__global__ __launch_bounds__(256) void prep_kernel(
    const float* __restrict__ audio,
    const float* __restrict__ w_ae, const float* __restrict__ w_a1,
    const float* __restrict__ w_a2, const float* __restrict__ w_f1,
    const float* __restrict__ w_f2, const float* __restrict__ heads_w,
    const float* __restrict__ heads_b,
    f16* __restrict__ a_h, f16* __restrict__ wae_t, f16* __restrict__ wa1_t,
    f16* __restrict__ wa2_t, f16* __restrict__ wf1_t, f16* __restrict__ wf2_t,
    f16* __restrict__ wh_t, float* __restrict__ bp, float* __restrict__ colsum)
{
  int idx = blockIdx.x * 256 + threadIdx.x;
  if (idx < 1048576) {  // a_h [8192][128], pad col>=80 with 0
    const int row = idx >> 7, col = idx & 127;
    a_h[idx] = (f16)(col < 80 ? audio[(size_t)row * 80 + col] : 0.f);
    return;
  }
  idx -= 1048576;
  if (idx < 32768) {    // wae_t [256][128]
    const int n = idx >> 7, k = idx & 127;
    wae_t[idx] = (f16)(k < 80 ? w_ae[k * 256 + n] : 0.f);
    return;
  }
  idx -= 32768;
  if (idx < 131072) { const int n = idx >> 8, k = idx & 255; wa1_t[idx] = (f16)w_a1[k * 512 + n]; return; }
  idx -= 131072;
  if (idx < 131072) { const int n = idx >> 9, k = idx & 511; wa2_t[idx] = (f16)w_a2[k * 256 + n]; return; }
  idx -= 131072;
  if (idx < 262144) { const int n = idx >> 9, k = idx & 511; wf1_t[idx] = (f16)w_f1[k * 512 + n]; return; }
  idx -= 262144;
  if (idx < 131072) { const int n = idx >> 9, k = idx & 511; wf2_t[idx] = (f16)w_f2[k * 256 + n]; return; }
  idx -= 131072;
  if (idx < 81920) {    // wh_t [320][256]
    const int n = idx >> 8, d = idx & 255;
    const int s = n / 80, o = n - s * 80;
    wh_t[idx] = (f16)heads_w[(size_t)(s * 256 + d) * 80 + o];
    return;
  }
  idx -= 81920;
  if (idx < 320) { bp[idx] = heads_b[idx]; return; }
  idx -= 320;
  if (idx < 2048) colsum[idx] = 0.f;
}

// ============================================================================
// LayerNorm(256) f32 -> f16. One wave per row.
// ============================================================================
__global__ __launch_bounds__(256) void layernorm_f16(
    const float* __restrict__ a, const float* __restrict__ g,
    const float* __restrict__ b, f16* __restrict__ out)
{
  const int row = blockIdx.x * 4 + (threadIdx.x >> 6);
  const int lane = threadIdx.x & 63;
  const float4 v = ((const float4*)(a + (size_t)row * 256))[lane];
  float s = v.x + v.y + v.z + v.w;
#pragma unroll
  for (int off = 32; off > 0; off >>= 1) s += __shfl_down(s, off);
  const float mu = __shfl(s, 0) * (1.0f / 256.0f);
  const float dx = v.x - mu, dy = v.y - mu, dz = v.z - mu, dw = v.w - mu;
  float s2 = dx * dx + dy * dy + dz * dz + dw * dw;
#pragma unroll
  for (int off = 32; off > 0; off >>= 1) s2 += __shfl_down(s2, off);
  const float var = __shfl(s2, 0) * (1.0f / 256.0f);
  const float r = rsqrtf(var + 1e-5f);
  const float4 gg = ((const float4*)g)[lane];
  const float4 bb = ((const float4*)b)[lane];
  f16x4 o;
  o[0] = (f16)(dx * r * gg.x + bb.x);
  o[1] = (f16)(dy * r * gg.y + bb.y);
  o[2] = (f16)(dz * r * gg.z + bb.z);
  o[3] = (f16)(dw * r * gg.w + bb.w);
  ((f16x4*)(out + (size_t)row * 256))[lane] = o;
}

// ============================================================================
// Video: conv7x7(s2,p3)+spatial-mean folded into 49 tap-sums per (n,c).
// ============================================================================
__global__ __launch_bounds__(256) void video_reduce_kernel(
    const float* __restrict__ x, float* __restrict__ Sg)
{
  const int img = blockIdx.x;
  const float* p = x + (size_t)img * 12544;
  __shared__ float rowS[2][112];
  __shared__ float c0s[112], c1s[112], c109s[112], c110s[112], c111s[112];
  __shared__ float base[14];
  __shared__ float sE[7], sO[7];
  const int t = threadIdx.x;
  if (t < 224) {
    const int r = t >> 1;
    const int par = t & 1;
    const float* rp = p + r * 112 + par;
    float s = 0.f;
#pragma unroll
    for (int i = 0; i < 56; i++) s += rp[2 * i];
    rowS[par][r] = s;
    if (par == 0) { c0s[r] = rp[0]; c110s[r] = rp[110]; }
    else { c1s[r] = rp[0]; c109s[r] = rp[108]; c111s[r] = rp[110]; }
  }
  __syncthreads();
  if (t < 14) {
    const int arr = t >> 1;
    const int rp = t & 1;
    const float* src = (arr == 0) ? rowS[0] : (arr == 1) ? rowS[1] :
                       (arr == 2) ? c0s : (arr == 3) ? c1s :
                       (arr == 4) ? c109s : (arr == 5) ? c110s : c111s;
    float s = 0.f;
    for (int r = rp; r < 112; r += 2) s += src[r];
    base[t] = s;
  }
  __syncthreads();
  if (t < 7) {
    float se, so;
    switch (t) {
      case 0: se = base[2] - base[8] - base[12]; so = base[3] - base[9] - base[13]; break;
      case 1: se = base[0] - base[10];           so = base[1] - base[11];           break;
      case 2: se = base[2] - base[12];           so = base[3] - base[13];           break;
      case 3: se = base[0];                      so = base[1];                      break;
      case 4: se = base[2];                      so = base[3];                      break;
      case 5: se = base[0] - base[4];            so = base[1] - base[5];            break;
      default: se = base[2] - base[6];           so = base[3] - base[7];            break;
    }
    sE[t] = se; sO[t] = so;
  }
  __syncthreads();
  if (t < 49) {
    const int kh = t / 7, kw = t % 7;
    auto ccol = [&](int r) -> float {
      switch (kw) {
        case 0: return rowS[1][r] - c109s[r] - c111s[r];
        case 1: return rowS[0][r] - c110s[r];
        case 2: return rowS[1][r] - c111s[r];
        case 3: return rowS[0][r];
        case 4: return rowS[1][r];
        case 5: return rowS[0][r] - c0s[r];
        default: return rowS[1][r] - c1s[r];
      }
    };
    float v;
    switch (kh) {
      case 0: v = sO[kw] - ccol(109) - ccol(111); break;
      case 1: v = sE[kw] - ccol(110);             break;
      case 2: v = sO[kw] - ccol(111);             break;
      case 3: v = sE[kw];                         break;
      case 4: v = sO[kw];                         break;
      case 5: v = sE[kw] - ccol(0);               break;
      default: v = sO[kw] - ccol(1);              break;
    }
    Sg[(size_t)img * 49 + t] = v;
  }
}

// ============================================================================
// Fused: vpool (49-tap conv+mean) + video FC 64->256.  One block per n (256).
// ============================================================================
__global__ __launch_bounds__(256) void vpool_fc_kernel(
    const float* __restrict__ Sg, const float* __restrict__ conv_w,
    const float* __restrict__ conv_b, const float* __restrict__ w_vfc,
    const float* __restrict__ b_vfc, float* __restrict__ v256)
{
  __shared__ float vp[64];
  const int n = blockIdx.x, t = threadIdx.x;
  if (t < 64) {
    float acc = 0.f;
    const float* s = Sg + (size_t)n * 147;
#pragma unroll 7
    for (int k = 0; k < 147; k++) acc = fmaf(conv_w[t * 147 + k], s[k], acc);
    vp[t] = conv_b[t] + acc * (1.0f / 3136.0f);
  }
  __syncthreads();
  float acc = 0.f;
#pragma unroll
  for (int k = 0; k < 64; k++) acc = fmaf(vp[k], w_vfc[k * 256 + t], acc);
  v256[(size_t)n * 256 + t] = acc + b_vfc[t];
}

// Temporal interp TV=32 -> T=1024, writes f16 into fbuf16 cols [256,512)
__global__ __launch_bounds__(256) void interp_video_f16(
    const float* __restrict__ v256, f16* __restrict__ fbuf)
{
  const int idx = blockIdx.x * 256 + threadIdx.x;
  const int c = idx & 255;
  const int t = (idx >> 8) & 1023;
  const int b = idx >> 18;
  float pos = ((float)t + 0.5f) * 0.03125f - 0.5f;
  pos = fminf(fmaxf(pos, 0.0f), 31.0f);
  const int lo = (int)floorf(pos);
  int hi = lo + 1; if (hi > 31) hi = 31;
  const float w = pos - (float)lo;
  const float vl = v256[(size_t)(b * 32 + lo) * 256 + c];
  const float vh = v256[(size_t)(b * 32 + hi) * 256 + c];
  fbuf[(size_t)(b * 1024 + t) * 512 + 256 + c] = (f16)(vl * (1.0f - w) + vh * w);
}

// energy[row] = sum over 80 cols of out_specs row  (row = (b*4+s)*1024+t)
__global__ __launch_bounds__(256) void energy_kernel(
    const float* __restrict__ specs, float* __restrict__ energy)
{
  const int row = blockIdx.x * 256 + threadIdx.x;   // 32768
  const float4* src = (const float4*)(specs + (size_t)row * 80);
  float sum = 0.f;
#pragma unroll
  for (int i = 0; i < 20; i++) {
    const float4 v = src[i];
    sum += v.x + v.y + v.z + v.w;
  }
  energy[row] = sum;
}

// ============================================================================
// Waveforms: JAX partitionable threefry2x32 (key=[0,1234]) + XLA erfinv
// ============================================================================
__device__ __forceinline__ unsigned rotl32(unsigned x, int d) {
  return (x << d) | (x >> (32 - d));
}

__device__ __forceinline__ float erfinv_xla(float x) {
  float w = -log1pf(-x * x);
  float p;
  if (w < 5.0f) {
    w = w - 2.5f;
    p = 2.81022636e-08f;
    p = fmaf(p, w, 3.43273939e-07f);
    p = fmaf(p, w, -3.5233877e-06f);
    p = fmaf(p, w, -4.39150654e-06f);
    p = fmaf(p, w, 0.00021858087f);
    p = fmaf(p, w, -0.00125372503f);
    p = fmaf(p, w, -0.00417768164f);
    p = fmaf(p, w, 0.246640727f);
    p = fmaf(p, w, 1.50140941f);
  } else {
    w = sqrtf(w) - 3.0f;
    p = -0.000200214257f;
    p = fmaf(p, w, 0.000100950558f);
    p = fmaf(p, w, 0.00134934322f);
    p = fmaf(p, w, -0.00367342844f);
    p = fmaf(p, w, 0.00573950773f);
    p = fmaf(p, w, -0.0076224613f);
    p = fmaf(p, w, 0.00943887047f);
    p = fmaf(p, w, 1.00167406f);
    p = fmaf(p, w, 2.83297682f);
  }
  return p * x;
}

__global__ __launch_bounds__(256) void waveform_kernel(
    const float* __restrict__ energy, float* __restrict__ out)
{
  const unsigned n = blockIdx.x * 256 + threadIdx.x;   // [0, 5242880)
  const unsigned ks0 = 0u, ks1 = 1234u;
  const unsigned ks2 = 0x1BD11BDAu ^ ks0 ^ ks1;
  unsigned x0 = ks0;
  unsigned x1 = n + ks1;
#define TF_R4(a, b, c, d)                        \
  x0 += x1; x1 = rotl32(x1, a); x1 ^= x0;        \
  x0 += x1; x1 = rotl32(x1, b); x1 ^= x0;        \
  x0 += x1; x1 = rotl32(x1, c); x1 ^= x0;        \
  x0 += x1; x1 = rotl32(x1, d); x1 ^= x0;
  TF_R4(13, 15, 26, 6)  x0 += ks1; x1 += ks2 + 1u;
  TF_R4(17, 29, 16, 24) x0 += ks2; x1 += ks0 + 2u;
  TF_R4(13, 15, 26, 6)  x0 += ks0; x1 += ks1 + 3u;
  TF_R4(17, 29, 16, 24) x0 += ks1; x1 += ks2 + 4u;
  TF_R4(13, 15, 26, 6)  x0 += ks2; x1 += ks0 + 5u;
#undef TF_R4
  const unsigned bits = x0 ^ x1;
  const float f = __uint_as_float((bits >> 9) | 0x3f800000u) - 1.0f;
  const float minv = -0.99999994f;
  const float u = fmaxf(minv, fmaf(f, 2.0f, minv));
  const float noise = 1.41421354f * erfinv_xla(u) * 0.1f;
  const unsigned i = n % 163840u;
  const unsigned bs = n / 163840u;
  float pos = ((float)i + 0.5f) * 0.00625f - 0.5f;
  pos = fminf(fmaxf(pos, 0.0f), 1023.0f);
  const int lo = (int)floorf(pos);
  int hi = lo + 1; if (hi > 1023) hi = 1023;
  const float w = pos - (float)lo;
  const float* e = energy + (size_t)bs * 1024;
  const float ev = e[lo] * (1.0f - w) + e[hi] * w;
  out[n] = noise * fmaf(ev, 0.5f, 0.5f);
}

// speaker_logits from colsum (filled by f2-GEMM epilogue atomics)
__global__ __launch_bounds__(64) void spk_final_kernel(
    const float* __restrict__ colsum, const float* __restrict__ w_spk,
    const float* __restrict__ b_spk, float* __restrict__ out)
{
  const int idx = threadIdx.x;
  if (idx < 32) {
    const int b = idx >> 2, s = idx & 3;
    const float* cs = colsum + b * 256;
    float acc = 0.f;
#pragma unroll 8
    for (int d = 0; d < 256; d++)
      acc = fmaf(cs[d] * (1.0f / 1024.0f), w_spk[d * 4 + s], acc);
    out[b * 4 + s] = acc + b_spk[s];
  }
}

// ============================================================================
extern "C" void kernel_launch(void* const* d_in, const int* in_sizes, int n_in,
                              void* d_out, int out_size, void* d_ws, size_t ws_size,
                              hipStream_t stream)
{
  (void)in_sizes; (void)n_in; (void)out_size; (void)ws_size;
  const float* audio   = (const float*)d_in[0];
  const float* video   = (const float*)d_in[1];
  const float* w_ae    = (const float*)d_in[2];
  const float* b_ae    = (const float*)d_in[3];
  const float* ln_g    = (const float*)d_in[4];
  const float* ln_b    = (const float*)d_in[5];
  const float* w_a1    = (const float*)d_in[6];
  const float* b_a1    = (const float*)d_in[7];
  const float* w_a2    = (const float*)d_in[8];
  const float* b_a2    = (const float*)d_in[9];
  const float* conv_w  = (const float*)d_in[10];
  const float* conv_b  = (const float*)d_in[11];
  const float* w_vfc   = (const float*)d_in[12];
  const float* b_vfc   = (const float*)d_in[13];
  const float* w_f1    = (const float*)d_in[14];
  const float* b_f1    = (const float*)d_in[15];
  const float* w_f2    = (const float*)d_in[16];
  const float* b_f2    = (const float*)d_in[17];
  const float* heads_w = (const float*)d_in[18];
  const float* heads_b = (const float*)d_in[19];
  const float* w_spk   = (const float*)d_in[20];
  const float* b_spk   = (const float*)d_in[21];

  float* ws = (float*)d_ws;
  float* a0     = ws;                 // 2,097,152 f32
  float* colsum = ws + 2097152;       // 2,048
  float* Sg     = ws + 2099200;       // 37,632
  float* v256   = ws + 2136832;       // 65,536
  float* energy = ws + 2202368;       // 32,768
  float* bp     = ws + 2235136;       // 320  (+pad to 2235456)
  f16* fh = (f16*)(ws + 2235456);
  f16* a1     = fh;                   // 2,097,152 f16
  f16* h16    = a1 + 2097152;         // 4,194,304
  f16* fbuf16 = h16 + 4194304;        // 4,194,304
  f16* a_h    = fbuf16 + 4194304;     // 1,048,576
  f16* wae_t  = a_h + 1048576;        //    32,768
  f16* wa1_t  = wae_t + 32768;        //   131,072
  f16* wa2_t  = wa1_t + 131072;       //   131,072
  f16* wf1_t  = wa2_t + 131072;       //   262,144
  f16* wf2_t  = wf1_t + 262144;       //   131,072
  f16* wh_t   = wf2_t + 131072;       //    81,920

  float* out_wave   = (float*)d_out;           // 5,242,880
  float* out_specs  = out_wave + 5242880;      // 2,621,440
  float* out_logits = out_specs + 2621440;     // 32

  // ---- prep: weight transposes + audio pad + colsum zero ----
  prep_kernel<<<7114, 256, 0, stream>>>(audio, w_ae, w_a1, w_a2, w_f1, w_f2,
                                        heads_w, heads_b,
                                        a_h, wae_t, wa1_t, wa2_t, wf1_t, wf2_t,
                                        wh_t, bp, colsum);

  // ---- video branch ----
  video_reduce_kernel<<<768, 256, 0, stream>>>(video, Sg);
  vpool_fc_kernel<<<256, 256, 0, stream>>>(Sg, conv_w, conv_b, w_vfc, b_vfc, v256);

  // ---- audio branch ----
  hgemm<0, 0><<<dim3(4, 64), 256, 0, stream>>>(a_h, wae_t, b_ae, a0, 256, 0, 256, 128, nullptr);
  layernorm_f16<<<2048, 256, 0, stream>>>(a0, ln_g, ln_b, a1);
  hgemm<1, 1><<<dim3(8, 64), 256, 0, stream>>>(a1, wa1_t, b_a1, h16, 512, 0, 512, 256, nullptr);
  hgemm<0, 1><<<dim3(4, 64), 256, 0, stream>>>(h16, wa2_t, b_a2, fbuf16, 512, 0, 256, 512, nullptr);
  interp_video_f16<<<8192, 256, 0, stream>>>(v256, fbuf16);

  // ---- fusion ----
  hgemm<1, 1><<<dim3(8, 64), 256, 0, stream>>>(fbuf16, wf1_t, b_f1, h16, 512, 0, 512, 512, nullptr);
  hgemm<0, 2><<<dim3(4, 64), 256, 0, stream>>>(h16, wf2_t, b_f2, a1, 256, 0, 256, 512, colsum);

  // ---- heads -> specs (direct [B,S,T,80] layout) + energy ----
  hgemm<0, 3><<<dim3(5, 64), 256, 0, stream>>>(a1, wh_t, bp, out_specs, 0, 0, 320, 256, nullptr);
  energy_kernel<<<128, 256, 0, stream>>>(out_specs, energy);

  // ---- waveforms ----
  waveform_kernel<<<20480, 256, 0, stream>>>(energy, out_wave);

  // ---- speaker logits ----
  spk_final_kernel<<<1, 64, 0, stream>>>(colsum, w_spk, b_spk, out_logits);
}

// Round 5
// 250.739 us; speedup vs baseline: 2.2118x; 1.0519x over previous
//
#include <hip/hip_runtime.h>
#include <hip/hip_bf16.h>
#include <math.h>

typedef _Float16 f16;
typedef f16 f16x8 __attribute__((ext_vector_type(8)));
typedef f16 f16x4 __attribute__((ext_vector_type(4)));
typedef float f32x4 __attribute__((ext_vector_type(4)));

// ============================================================================
// fp16 MFMA GEMM: C[M,N] = A[M,K](f16) @ Wt[N,K]^T(f16) + bias(f32)
// Tile 64(M) x 64(N), BK=64, 256 threads = 4 waves, wave tile 32x32.
// Double-buffered LDS (ping-pong, ONE barrier per K-iter) + register
// prefetch: iter k+1's global loads issue before barrier_k, overlapping
// iter k's ds_read+MFMA. Grid = (N/64, M/64) -> 512-1024 blocks (2-4/CU).
// LDS rows are 128B with XOR-swizzled 16B granules (b128 min-phase access).
// OUT: 0 = f32 store; 1 = f16 store; 2 = f16 store + colsum atomics (speaker);
//      3 = f32 store remapped to specs [B,S,T,80] layout.
// ============================================================================
template<int RELU, int OUT>
__global__ __launch_bounds__(256) void hgemm(
    const f16* __restrict__ A, const f16* __restrict__ Wt,
    const float* __restrict__ bias,
    void* __restrict__ Cout, int ldc, int col_off,
    int N, int K, float* __restrict__ colsum)
{
  __shared__ f16 As[2][64 * 64];   // 8 KB each
  __shared__ f16 Bs[2][64 * 64];
  const int tid = threadIdx.x;
  const int wave = tid >> 6, lane = tid & 63;
  const int wm = (wave >> 1) * 32;
  const int wn = (wave & 1) * 32;
  const int m0 = blockIdx.y * 64;
  const int n0 = blockIdx.x * 64;
  const int q = lane >> 4, r16 = lane & 15;

  // staging coords: granule c in [0,512): row=c>>3 (64 rows), g=c&7
  const int c0 = tid, c1 = tid + 256;
  const int rA0 = c0 >> 3, gA0 = c0 & 7;
  const int rA1 = c1 >> 3, gA1 = c1 & 7;

  const f16* pA0 = A + (size_t)(m0 + rA0) * K + gA0 * 8;
  const f16* pA1 = A + (size_t)(m0 + rA1) * K + gA1 * 8;
  const f16* pB0 = Wt + (size_t)(n0 + rA0) * K + gA0 * 8;
  const f16* pB1 = Wt + (size_t)(n0 + rA1) * K + gA1 * 8;

  // swizzled LDS byte offsets for staging writes
  const int sA0 = rA0 * 128 + ((gA0 ^ (rA0 & 7)) * 16);
  const int sA1 = rA1 * 128 + ((gA1 ^ (rA1 & 7)) * 16);

  f32x4 acc[2][2];
#pragma unroll
  for (int mi = 0; mi < 2; mi++)
#pragma unroll
    for (int ni = 0; ni < 2; ni++) acc[mi][ni] = (f32x4)0.f;

  // prologue: load iter 0
  f16x8 ar0 = *(const f16x8*)pA0;
  f16x8 ar1 = *(const f16x8*)pA1;
  f16x8 br0 = *(const f16x8*)pB0;
  f16x8 br1 = *(const f16x8*)pB1;

  const int iters = K >> 6;
  int p = 0;
  for (int it = 0; it < iters; it++) {
    // regs -> LDS buf p (compiler inserts vmcnt wait on the pending loads)
    *(f16x8*)((char*)As[p] + sA0) = ar0;
    *(f16x8*)((char*)As[p] + sA1) = ar1;
    *(f16x8*)((char*)Bs[p] + sA0) = br0;
    *(f16x8*)((char*)Bs[p] + sA1) = br1;
    // prefetch iter it+1 (overlaps with this iter's compute)
    if (it + 1 < iters) {
      const int ko = (it + 1) << 6;
      ar0 = *(const f16x8*)(pA0 + ko);
      ar1 = *(const f16x8*)(pA1 + ko);
      br0 = *(const f16x8*)(pB0 + ko);
      br1 = *(const f16x8*)(pB1 + ko);
    }
    __syncthreads();
#pragma unroll
    for (int h = 0; h < 2; h++) {
      const int kg = h * 4 + q;
      f16x8 af[2], bf[2];
#pragma unroll
      for (int mi = 0; mi < 2; mi++) {
        const int row = wm + mi * 16 + r16;
        af[mi] = *(const f16x8*)((char*)As[p] + row * 128 + ((kg ^ (row & 7)) * 16));
      }
#pragma unroll
      for (int ni = 0; ni < 2; ni++) {
        const int row = wn + ni * 16 + r16;
        bf[ni] = *(const f16x8*)((char*)Bs[p] + row * 128 + ((kg ^ (row & 7)) * 16));
      }
#pragma unroll
      for (int mi = 0; mi < 2; mi++)
#pragma unroll
        for (int ni = 0; ni < 2; ni++)
          acc[mi][ni] = __builtin_amdgcn_mfma_f32_16x16x32_f16(
              af[mi], bf[ni], acc[mi][ni], 0, 0, 0);
    }
    p ^= 1;
  }

#pragma unroll
  for (int ni = 0; ni < 2; ni++) {
    const int n = n0 + wn + ni * 16 + r16;
    const float bv = bias[n];
    const int s_ = n / 80, o_ = n - s_ * 80;   // OUT==3 only
    float csum = 0.f;
#pragma unroll
    for (int mi = 0; mi < 2; mi++) {
#pragma unroll
      for (int rr = 0; rr < 4; rr++) {
        const int m = m0 + wm + mi * 16 + q * 4 + rr;
        float v = acc[mi][ni][rr] + bv;
        if (RELU) v = fmaxf(v, 0.f);
        if (OUT == 2) csum += v;
        if (OUT == 0)
          ((float*)Cout)[(size_t)m * ldc + col_off + n] = v;
        else if (OUT == 3) {
          const int b_ = m >> 10, t_ = m & 1023;
          ((float*)Cout)[((size_t)((b_ * 4 + s_) * 1024 + t_)) * 80 + o_] = v;
        } else
          ((f16*)Cout)[(size_t)m * ldc + col_off + n] = (f16)v;
      }
    }
    if (OUT == 2) {
      csum += __shfl_xor(csum, 16);
      csum += __shfl_xor(csum, 32);
      if (q == 0) atomicAdd(&colsum[(m0 >> 10) * 256 + n], csum);
    }
  }
}

// ============================================================================
// Prep: all weight transposes to [N][K] f16, audio pad->f16, bias copy,
// colsum zero. One dispatch.
// ============================================================================
__global__ __launch_bounds__(256) void prep_kernel(
    const float* __restrict__ audio,
    const float* __restrict__ w_ae, const float* __restrict__ w_a1,
    const float* __restrict__ w_a2, const float* __restrict__ w_f1,
    const float* __restrict__ w_f2, const float* __restrict__ heads_w,
    const float* __restrict__ heads_b,
    f16* __restrict__ a_h, f16* __restrict__ wae_t, f16* __restrict__ wa1_t,
    f16* __restrict__ wa2_t, f16* __restrict__ wf1_t, f16* __restrict__ wf2_t,
    f16* __restrict__ wh_t, float* __restrict__ bp, float* __restrict__ colsum)
{
  int idx = blockIdx.x * 256 + threadIdx.x;
  if (idx < 1048576) {  // a_h [8192][128], pad col>=80 with 0
    const int row = idx >> 7, col = idx & 127;
    a_h[idx] = (f16)(col < 80 ? audio[(size_t)row * 80 + col] : 0.f);
    return;
  }
  idx -= 1048576;
  if (idx < 32768) {    // wae_t [256][128]
    const int n = idx >> 7, k = idx & 127;
    wae_t[idx] = (f16)(k < 80 ? w_ae[k * 256 + n] : 0.f);
    return;
  }
  idx -= 32768;
  if (idx < 131072) { const int n = idx >> 8, k = idx & 255; wa1_t[idx] = (f16)w_a1[k * 512 + n]; return; }
  idx -= 131072;
  if (idx < 131072) { const int n = idx >> 9, k = idx & 511; wa2_t[idx] = (f16)w_a2[k * 256 + n]; return; }
  idx -= 131072;
  if (idx < 262144) { const int n = idx >> 9, k = idx & 511; wf1_t[idx] = (f16)w_f1[k * 512 + n]; return; }
  idx -= 262144;
  if (idx < 131072) { const int n = idx >> 9, k = idx & 511; wf2_t[idx] = (f16)w_f2[k * 256 + n]; return; }
  idx -= 131072;
  if (idx < 81920) {    // wh_t [320][256]
    const int n = idx >> 8, d = idx & 255;
    const int s = n / 80, o = n - s * 80;
    wh_t[idx] = (f16)heads_w[(size_t)(s * 256 + d) * 80 + o];
    return;
  }
  idx -= 81920;
  if (idx < 320) { bp[idx] = heads_b[idx]; return; }
  idx -= 320;
  if (idx < 2048) colsum[idx] = 0.f;
}

// ============================================================================
// LayerNorm(256) f32 -> f16. One wave per row.
// ============================================================================
__global__ __launch_bounds__(256) void layernorm_f16(
    const float* __restrict__ a, const float* __restrict__ g,
    const float* __restrict__ b, f16* __restrict__ out)
{
  const int row = blockIdx.x * 4 + (threadIdx.x >> 6);
  const int lane = threadIdx.x & 63;
  const float4 v = ((const float4*)(a + (size_t)row * 256))[lane];
  float s = v.x + v.y + v.z + v.w;
#pragma unroll
  for (int off = 32; off > 0; off >>= 1) s += __shfl_down(s, off);
  const float mu = __shfl(s, 0) * (1.0f / 256.0f);
  const float dx = v.x - mu, dy = v.y - mu, dz = v.z - mu, dw = v.w - mu;
  float s2 = dx * dx + dy * dy + dz * dz + dw * dw;
#pragma unroll
  for (int off = 32; off > 0; off >>= 1) s2 += __shfl_down(s2, off);
  const float var = __shfl(s2, 0) * (1.0f / 256.0f);
  const float r = rsqrtf(var + 1e-5f);
  const float4 gg = ((const float4*)g)[lane];
  const float4 bb = ((const float4*)b)[lane];
  f16x4 o;
  o[0] = (f16)(dx * r * gg.x + bb.x);
  o[1] = (f16)(dy * r * gg.y + bb.y);
  o[2] = (f16)(dz * r * gg.z + bb.z);
  o[3] = (f16)(dw * r * gg.w + bb.w);
  ((f16x4*)(out + (size_t)row * 256))[lane] = o;
}

// ============================================================================
// Video: conv7x7(s2,p3)+spatial-mean folded into 49 tap-sums per (n,c).
// ============================================================================
__global__ __launch_bounds__(256) void video_reduce_kernel(
    const float* __restrict__ x, float* __restrict__ Sg)
{
  const int img = blockIdx.x;
  const float* p = x + (size_t)img * 12544;
  __shared__ float rowS[2][112];
  __shared__ float c0s[112], c1s[112], c109s[112], c110s[112], c111s[112];
  __shared__ float base[14];
  __shared__ float sE[7], sO[7];
  const int t = threadIdx.x;
  if (t < 224) {
    const int r = t >> 1;
    const int par = t & 1;
    const float* rp = p + r * 112 + par;
    float s = 0.f;
#pragma unroll
    for (int i = 0; i < 56; i++) s += rp[2 * i];
    rowS[par][r] = s;
    if (par == 0) { c0s[r] = rp[0]; c110s[r] = rp[110]; }
    else { c1s[r] = rp[0]; c109s[r] = rp[108]; c111s[r] = rp[110]; }
  }
  __syncthreads();
  if (t < 14) {
    const int arr = t >> 1;
    const int rp = t & 1;
    const float* src = (arr == 0) ? rowS[0] : (arr == 1) ? rowS[1] :
                       (arr == 2) ? c0s : (arr == 3) ? c1s :
                       (arr == 4) ? c109s : (arr == 5) ? c110s : c111s;
    float s = 0.f;
    for (int r = rp; r < 112; r += 2) s += src[r];
    base[t] = s;
  }
  __syncthreads();
  if (t < 7) {
    float se, so;
    switch (t) {
      case 0: se = base[2] - base[8] - base[12]; so = base[3] - base[9] - base[13]; break;
      case 1: se = base[0] - base[10];           so = base[1] - base[11];           break;
      case 2: se = base[2] - base[12];           so = base[3] - base[13];           break;
      case 3: se = base[0];                      so = base[1];                      break;
      case 4: se = base[2];                      so = base[3];                      break;
      case 5: se = base[0] - base[4];            so = base[1] - base[5];            break;
      default: se = base[2] - base[6];           so = base[3] - base[7];            break;
    }
    sE[t] = se; sO[t] = so;
  }
  __syncthreads();
  if (t < 49) {
    const int kh = t / 7, kw = t % 7;
    auto ccol = [&](int r) -> float {
      switch (kw) {
        case 0: return rowS[1][r] - c109s[r] - c111s[r];
        case 1: return rowS[0][r] - c110s[r];
        case 2: return rowS[1][r] - c111s[r];
        case 3: return rowS[0][r];
        case 4: return rowS[1][r];
        case 5: return rowS[0][r] - c0s[r];
        default: return rowS[1][r] - c1s[r];
      }
    };
    float v;
    switch (kh) {
      case 0: v = sO[kw] - ccol(109) - ccol(111); break;
      case 1: v = sE[kw] - ccol(110);             break;
      case 2: v = sO[kw] - ccol(111);             break;
      case 3: v = sE[kw];                         break;
      case 4: v = sO[kw];                         break;
      case 5: v = sE[kw] - ccol(0);               break;
      default: v = sO[kw] - ccol(1);              break;
    }
    Sg[(size_t)img * 49 + t] = v;
  }
}

// ============================================================================
// Fused: vpool (49-tap conv+mean) + video FC 64->256.  One block per n (256).
// ============================================================================
__global__ __launch_bounds__(256) void vpool_fc_kernel(
    const float* __restrict__ Sg, const float* __restrict__ conv_w,
    const float* __restrict__ conv_b, const float* __restrict__ w_vfc,
    const float* __restrict__ b_vfc, float* __restrict__ v256)
{
  __shared__ float vp[64];
  const int n = blockIdx.x, t = threadIdx.x;
  if (t < 64) {
    float acc = 0.f;
    const float* s = Sg + (size_t)n * 147;
#pragma unroll 7
    for (int k = 0; k < 147; k++) acc = fmaf(conv_w[t * 147 + k], s[k], acc);
    vp[t] = conv_b[t] + acc * (1.0f / 3136.0f);
  }
  __syncthreads();
  float acc = 0.f;
#pragma unroll
  for (int k = 0; k < 64; k++) acc = fmaf(vp[k], w_vfc[k * 256 + t], acc);
  v256[(size_t)n * 256 + t] = acc + b_vfc[t];
}

// Temporal interp TV=32 -> T=1024, writes f16 into fbuf16 cols [256,512)
__global__ __launch_bounds__(256) void interp_video_f16(
    const float* __restrict__ v256, f16* __restrict__ fbuf)
{
  const int idx = blockIdx.x * 256 + threadIdx.x;
  const int c = idx & 255;
  const int t = (idx >> 8) & 1023;
  const int b = idx >> 18;
  float pos = ((float)t + 0.5f) * 0.03125f - 0.5f;
  pos = fminf(fmaxf(pos, 0.0f), 31.0f);
  const int lo = (int)floorf(pos);
  int hi = lo + 1; if (hi > 31) hi = 31;
  const float w = pos - (float)lo;
  const float vl = v256[(size_t)(b * 32 + lo) * 256 + c];
  const float vh = v256[(size_t)(b * 32 + hi) * 256 + c];
  fbuf[(size_t)(b * 1024 + t) * 512 + 256 + c] = (f16)(vl * (1.0f - w) + vh * w);
}

// energy[row] = sum over 80 cols of out_specs row  (row = (b*4+s)*1024+t)
__global__ __launch_bounds__(256) void energy_kernel(
    const float* __restrict__ specs, float* __restrict__ energy)
{
  const int row = blockIdx.x * 256 + threadIdx.x;   // 32768
  const float4* src = (const float4*)(specs + (size_t)row * 80);
  float sum = 0.f;
#pragma unroll
  for (int i = 0; i < 20; i++) {
    const float4 v = src[i];
    sum += v.x + v.y + v.z + v.w;
  }
  energy[row] = sum;
}

// ============================================================================
// Waveforms: JAX partitionable threefry2x32 (key=[0,1234]) + XLA erfinv
// ============================================================================
__device__ __forceinline__ unsigned rotl32(unsigned x, int d) {
  return (x << d) | (x >> (32 - d));
}

__device__ __forceinline__ float erfinv_xla(float x) {
  float w = -log1pf(-x * x);
  float p;
  if (w < 5.0f) {
    w = w - 2.5f;
    p = 2.81022636e-08f;
    p = fmaf(p, w, 3.43273939e-07f);
    p = fmaf(p, w, -3.5233877e-06f);
    p = fmaf(p, w, -4.39150654e-06f);
    p = fmaf(p, w, 0.00021858087f);
    p = fmaf(p, w, -0.00125372503f);
    p = fmaf(p, w, -0.00417768164f);
    p = fmaf(p, w, 0.246640727f);
    p = fmaf(p, w, 1.50140941f);
  } else {
    w = sqrtf(w) - 3.0f;
    p = -0.000200214257f;
    p = fmaf(p, w, 0.000100950558f);
    p = fmaf(p, w, 0.00134934322f);
    p = fmaf(p, w, -0.00367342844f);
    p = fmaf(p, w, 0.00573950773f);
    p = fmaf(p, w, -0.0076224613f);
    p = fmaf(p, w, 0.00943887047f);
    p = fmaf(p, w, 1.00167406f);
    p = fmaf(p, w, 2.83297682f);
  }
  return p * x;
}

__global__ __launch_bounds__(256) void waveform_kernel(
    const float* __restrict__ energy, float* __restrict__ out)
{
  const unsigned n = blockIdx.x * 256 + threadIdx.x;   // [0, 5242880)
  const unsigned ks0 = 0u, ks1 = 1234u;
  const unsigned ks2 = 0x1BD11BDAu ^ ks0 ^ ks1;
  unsigned x0 = ks0;
  unsigned x1 = n + ks1;
#define TF_R4(a, b, c, d)                        \
  x0 += x1; x1 = rotl32(x1, a); x1 ^= x0;        \
  x0 += x1; x1 = rotl32(x1, b); x1 ^= x0;        \
  x0 += x1; x1 = rotl32(x1, c); x1 ^= x0;        \
  x0 += x1; x1 = rotl32(x1, d); x1 ^= x0;
  TF_R4(13, 15, 26, 6)  x0 += ks1; x1 += ks2 + 1u;
  TF_R4(17, 29, 16, 24) x0 += ks2; x1 += ks0 + 2u;
  TF_R4(13, 15, 26, 6)  x0 += ks0; x1 += ks1 + 3u;
  TF_R4(17, 29, 16, 24) x0 += ks1; x1 += ks2 + 4u;
  TF_R4(13, 15, 26, 6)  x0 += ks2; x1 += ks0 + 5u;
#undef TF_R4
  const unsigned bits = x0 ^ x1;
  const float f = __uint_as_float((bits >> 9) | 0x3f800000u) - 1.0f;
  const float minv = -0.99999994f;
  const float u = fmaxf(minv, fmaf(f, 2.0f, minv));
  const float noise = 1.41421354f * erfinv_xla(u) * 0.1f;
  const unsigned i = n % 163840u;
  const unsigned bs = n / 163840u;
  float pos = ((float)i + 0.5f) * 0.00625f - 0.5f;
  pos = fminf(fmaxf(pos, 0.0f), 1023.0f);
  const int lo = (int)floorf(pos);
  int hi = lo + 1; if (hi > 1023) hi = 1023;
  const float w = pos - (float)lo;
  const float* e = energy + (size_t)bs * 1024;
  const float ev = e[lo] * (1.0f - w) + e[hi] * w;
  out[n] = noise * fmaf(ev, 0.5f, 0.5f);
}

// speaker_logits from colsum (filled by f2-GEMM epilogue atomics)
__global__ __launch_bounds__(64) void spk_final_kernel(
    const float* __restrict__ colsum, const float* __restrict__ w_spk,
    const float* __restrict__ b_spk, float* __restrict__ out)
{
  const int idx = threadIdx.x;
  if (idx < 32) {
    const int b = idx >> 2, s = idx & 3;
    const float* cs = colsum + b * 256;
    float acc = 0.f;
#pragma unroll 8
    for (int d = 0; d < 256; d++)
      acc = fmaf(cs[d] * (1.0f / 1024.0f), w_spk[d * 4 + s], acc);
    out[b * 4 + s] = acc + b_spk[s];
  }
}

// ============================================================================
extern "C" void kernel_launch(void* const* d_in, const int* in_sizes, int n_in,
                              void* d_out, int out_size, void* d_ws, size_t ws_size,
                              hipStream_t stream)
{
  (void)in_sizes; (void)n_in; (void)out_size; (void)ws_size;
  const float* audio   = (const float*)d_in[0];
  const float* video   = (const float*)d_in[1];
  const float* w_ae    = (const float*)d_in[2];
  const float* b_ae    = (const float*)d_in[3];
  const float* ln_g    = (const float*)d_in[4];
  const float* ln_b    = (const float*)d_in[5];
  const float* w_a1    = (const float*)d_in[6];
  const float* b_a1    = (const float*)d_in[7];
  const float* w_a2    = (const float*)d_in[8];
  const float* b_a2    = (const float*)d_in[9];
  const float* conv_w  = (const float*)d_in[10];
  const float* conv_b  = (const float*)d_in[11];
  const float* w_vfc   = (const float*)d_in[12];
  const float* b_vfc   = (const float*)d_in[13];
  const float* w_f1    = (const float*)d_in[14];
  const float* b_f1    = (const float*)d_in[15];
  const float* w_f2    = (const float*)d_in[16];
  const float* b_f2    = (const float*)d_in[17];
  const float* heads_w = (const float*)d_in[18];
  const float* heads_b = (const float*)d_in[19];
  const float* w_spk   = (const float*)d_in[20];
  const float* b_spk   = (const float*)d_in[21];

  float* ws = (float*)d_ws;
  float* a0     = ws;                 // 2,097,152 f32
  float* colsum = ws + 2097152;       // 2,048
  float* Sg     = ws + 2099200;       // 37,632
  float* v256   = ws + 2136832;       // 65,536
  float* energy = ws + 2202368;       // 32,768
  float* bp     = ws + 2235136;       // 320  (+pad to 2235456)
  f16* fh = (f16*)(ws + 2235456);
  f16* a1     = fh;                   // 2,097,152 f16
  f16* h16    = a1 + 2097152;         // 4,194,304
  f16* fbuf16 = h16 + 4194304;        // 4,194,304
  f16* a_h    = fbuf16 + 4194304;     // 1,048,576
  f16* wae_t  = a_h + 1048576;        //    32,768
  f16* wa1_t  = wae_t + 32768;        //   131,072
  f16* wa2_t  = wa1_t + 131072;       //   131,072
  f16* wf1_t  = wa2_t + 131072;       //   262,144
  f16* wf2_t  = wf1_t + 262144;       //   131,072
  f16* wh_t   = wf2_t + 131072;       //    81,920

  float* out_wave   = (float*)d_out;           // 5,242,880
  float* out_specs  = out_wave + 5242880;      // 2,621,440
  float* out_logits = out_specs + 2621440;     // 32

  // ---- prep: weight transposes + audio pad + colsum zero ----
  prep_kernel<<<7114, 256, 0, stream>>>(audio, w_ae, w_a1, w_a2, w_f1, w_f2,
                                        heads_w, heads_b,
                                        a_h, wae_t, wa1_t, wa2_t, wf1_t, wf2_t,
                                        wh_t, bp, colsum);

  // ---- video branch ----
  video_reduce_kernel<<<768, 256, 0, stream>>>(video, Sg);
  vpool_fc_kernel<<<256, 256, 0, stream>>>(Sg, conv_w, conv_b, w_vfc, b_vfc, v256);

  // ---- audio branch ----
  hgemm<0, 0><<<dim3(4, 128), 256, 0, stream>>>(a_h, wae_t, b_ae, a0, 256, 0, 256, 128, nullptr);
  layernorm_f16<<<2048, 256, 0, stream>>>(a0, ln_g, ln_b, a1);
  hgemm<1, 1><<<dim3(8, 128), 256, 0, stream>>>(a1, wa1_t, b_a1, h16, 512, 0, 512, 256, nullptr);
  hgemm<0, 1><<<dim3(4, 128), 256, 0, stream>>>(h16, wa2_t, b_a2, fbuf16, 512, 0, 256, 512, nullptr);
  interp_video_f16<<<8192, 256, 0, stream>>>(v256, fbuf16);

  // ---- fusion ----
  hgemm<1, 1><<<dim3(8, 128), 256, 0, stream>>>(fbuf16, wf1_t, b_f1, h16, 512, 0, 512, 512, nullptr);
  hgemm<0, 2><<<dim3(4, 128), 256, 0, stream>>>(h16, wf2_t, b_f2, a1, 256, 0, 256, 512, colsum);

  // ---- heads -> specs (direct [B,S,T,80] layout) + energy ----
  hgemm<0, 3><<<dim3(5, 128), 256, 0, stream>>>(a1, wh_t, bp, out_specs, 0, 0, 320, 256, nullptr);
  energy_kernel<<<128, 256, 0, stream>>>(out_specs, energy);

  // ---- waveforms ----
  waveform_kernel<<<20480, 256, 0, stream>>>(energy, out_wave);

  // ---- speaker logits ----
  spk_final_kernel<<<1, 64, 0, stream>>>(colsum, w_spk, b_spk, out_logits);
}